// Round 8
// baseline (576.303 us; speedup 1.0000x reference)
//
#include <hip/hip_runtime.h>
#include <hip/hip_bf16.h>
#include <hip/hip_cooperative_groups.h>

namespace cg = cooperative_groups;

#define B_ 32
#define C_ 1000
#define H_ 512
#define NP 1024   // padded node count (N=1001 real)

typedef __attribute__((ext_vector_type(4))) int i32x4;

// tile order per mb: 28 off-diag first, 8 diag last (round 3 of grid-stride = diag only)
__device__ const unsigned char TI36[36] = {0,0,0,0,0,0,0, 1,1,1,1,1,1, 2,2,2,2,2, 3,3,3,3, 4,4,4, 5,5, 6, 0,1,2,3,4,5,6,7};
__device__ const unsigned char TJ36[36] = {1,2,3,4,5,6,7, 2,3,4,5,6,7, 3,4,5,6,7, 4,5,6,7, 5,6,7, 6,7, 7, 0,1,2,3,4,5,6,7};

__device__ __forceinline__ float tanh_fast(float x) {
  float ax = fminf(fabsf(x), 15.0f);
  float e = __expf(2.0f * ax);
  float t = (e - 1.0f) / (e + 1.0f);
  return copysignf(t, x);
}
__device__ __forceinline__ float sc2f(unsigned v) {   // sext low byte -> float
  return (float)(int)(signed char)v;
}
__device__ __forceinline__ void gload16(const void* g, void* l) {
  __builtin_amdgcn_global_load_lds((const __attribute__((address_space(1))) unsigned*)g,
                                   (__attribute__((address_space(3))) unsigned*)l, 16, 0, 0);
}

__global__ __launch_bounds__(256, 4) void k_mega(
    const float* __restrict__ it, const float* __restrict__ ii,
    const float* __restrict__ bt, const float* __restrict__ bi,
    const float* __restrict__ Wtt, const float* __restrict__ btt,
    const float* __restrict__ Wit, const float* __restrict__ bit,
    signed char* __restrict__ xq, float* __restrict__ nrm, float* __restrict__ qs,
    float* __restrict__ sc, float* __restrict__ r, float* __restrict__ y,
    float* __restrict__ go, float* __restrict__ out) {
  cg::grid_group grid = cg::this_grid();
  __shared__ __align__(16) unsigned char smem[33792];   // gram: As 16K | Bs 16K | s_qs 1K
  const int nb = gridDim.x;
  const int tid = threadIdx.x;
  const int w = tid >> 6, lane = tid & 63;

  // ================= phase 0: normalize -> i8 quant; zero r/y/go =================
  for (int u = blockIdx.x; u < 16384; u += nb) {
    int zi = u * 256 + tid;
    if (zi < 114688) r[zi] = 0.0f;               // r,y,go contiguous

    int wid = u * 4 + w;
    int node = wid & (NP - 1);
    int mb = wid >> 10;
    int b = mb & 31, mod = mb >> 5;
    const float* src = nullptr;
    if (node == 0) src = (mod ? ii : it) + b * H_;
    else if (node <= C_) src = (mod ? bi : bt) + ((size_t)b * C_ + (node - 1)) * H_;
    float4 v0 = make_float4(0.f, 0.f, 0.f, 0.f), v1 = v0;
    if (src) {
      const float4* s4 = (const float4*)src;
      v0 = s4[lane * 2]; v1 = s4[lane * 2 + 1];
    }
    float ss = v0.x*v0.x + v0.y*v0.y + v0.z*v0.z + v0.w*v0.w
             + v1.x*v1.x + v1.y*v1.y + v1.z*v1.z + v1.w*v1.w;
    #pragma unroll
    for (int o = 32; o; o >>= 1) ss += __shfl_xor(ss, o);
    float n = sqrtf(ss);
    if (lane == 0) nrm[wid] = n;
    float inv = 1.0f / fmaxf(n, 1e-12f);
    float x[8] = {v0.x*inv, v0.y*inv, v0.z*inv, v0.w*inv, v1.x*inv, v1.y*inv, v1.z*inv, v1.w*inv};
    float m8 = 0.f;
    #pragma unroll
    for (int j = 0; j < 8; ++j) m8 = fmaxf(m8, fabsf(x[j]));
    #pragma unroll
    for (int o = 32; o; o >>= 1) m8 = fmaxf(m8, __shfl_xor(m8, o));
    if (lane == 0) qs[wid] = m8 * (1.0f / 127.0f);
    float invq = (m8 > 0.f) ? 127.0f / m8 : 0.f;
    int q[8];
    #pragma unroll
    for (int j = 0; j < 8; ++j) q[j] = __float2int_rn(x[j] * invq);
    unsigned lo = (q[0] & 255) | ((q[1] & 255) << 8) | ((q[2] & 255) << 16) | ((unsigned)(q[3] & 255) << 24);
    unsigned hi = (q[4] & 255) | ((q[5] & 255) << 8) | ((q[6] & 255) << 16) | ((unsigned)(q[7] & 255) << 24);
    *(uint2*)(xq + (size_t)wid * H_ + lane * 8) = make_uint2(lo, hi);
  }
  __threadfence();
  grid.sync();

  // ================= phase 1: i8 Gram row-sums, symmetric, dbuf + counted vmcnt =================
  {
    unsigned char* As = smem;
    unsigned char* Bs = smem + 16384;
    float* s_qs = (float*)(smem + 32768);
    const int wr = w >> 1, wc = w & 1;
    const int lrow = lane >> 2;   // row within 16-row staging chunk
    const int ps0 = lane & 3;     // physical 16B segment

    for (int u = blockIdx.x; u < 2304; u += nb) {   // u%8 == blockIdx.x%8 (nb%8==0) -> XCD-pinned
      int mb = u & 63;
      int o = u >> 6;
      int ti = TI36[o], tj = TJ36[o];
      bool diag = (ti == tj);
      const signed char* X = xq + (size_t)mb * NP * H_;

      __syncthreads();   // previous tile's epilogue reads of s_qs done
      if (tid < 128) s_qs[tid] = qs[mb * NP + ti * 128 + tid];
      else           s_qs[tid] = qs[mb * NP + tj * 128 + (tid - 128)];

      i32x4 acc[4][4] = {};
      auto stage = [&](int buf, int ks) {
        #pragma unroll
        for (int q = 0; q < 2; ++q) {
          int chunk = w * 2 + q;
          int row = chunk * 16 + lrow;
          int qq = ps0 ^ ((row >> 1) & 3);
          gload16(X + (size_t)(ti * 128 + row) * H_ + ks * 64 + qq * 16,
                  (void*)(As + buf * 8192 + chunk * 1024));
          if (!diag)
            gload16(X + (size_t)(tj * 128 + row) * H_ + ks * 64 + qq * 16,
                    (void*)(Bs + buf * 8192 + chunk * 1024));
        }
      };

      stage(0, 0);          // per-wave loads per stage: 4 (non-diag) / 2 (diag)
      stage(1, 1);
      #pragma unroll
      for (int ks = 0; ks < 8; ++ks) {
        if (ks < 7) {
          if (diag) asm volatile("s_waitcnt vmcnt(2)" ::: "memory");
          else      asm volatile("s_waitcnt vmcnt(4)" ::: "memory");
        } else {
          asm volatile("s_waitcnt vmcnt(0)" ::: "memory");
        }
        __builtin_amdgcn_s_barrier();           // buf[ks&1] fully staged
        const unsigned char* Ab = As + (ks & 1) * 8192;
        const unsigned char* Bb = (diag ? As : Bs) + (ks & 1) * 8192;
        i32x4 af[4], bf[4];
        #pragma unroll
        for (int mi = 0; mi < 4; ++mi) {
          int row = wr * 64 + mi * 16 + (lane & 15);
          int ps = (lane >> 4) ^ ((row >> 1) & 3);
          af[mi] = *(const i32x4*)(Ab + row * 64 + ps * 16);
        }
        #pragma unroll
        for (int ni = 0; ni < 4; ++ni) {
          int row = wc * 64 + ni * 16 + (lane & 15);
          int ps = (lane >> 4) ^ ((row >> 1) & 3);
          bf[ni] = *(const i32x4*)(Bb + row * 64 + ps * 16);
        }
        #pragma unroll
        for (int mi = 0; mi < 4; ++mi)
          #pragma unroll
          for (int ni = 0; ni < 4; ++ni)
            acc[mi][ni] = __builtin_amdgcn_mfma_i32_16x16x64_i8(af[mi], bf[ni], acc[mi][ni], 0, 0, 0);
        __builtin_amdgcn_s_barrier();           // all reads of buf[ks&1] retired
        if (ks < 6) stage(ks & 1, ks + 2);
      }

      __syncthreads();   // s_qs visible; LDS idle
      float* rr = r + mb * NP;
      float qsc[4];
      #pragma unroll
      for (int ni = 0; ni < 4; ++ni) qsc[ni] = s_qs[128 + wc * 64 + ni * 16 + (lane & 15)];
      #pragma unroll
      for (int mi = 0; mi < 4; ++mi) {
        #pragma unroll
        for (int reg = 0; reg < 4; ++reg) {
          float v = 0.f;
          #pragma unroll
          for (int ni = 0; ni < 4; ++ni) {
            int d = acc[mi][ni][reg];
            v += (d > 0 ? (float)d : 0.f) * qsc[ni];
          }
          v += __shfl_xor(v, 1); v += __shfl_xor(v, 2); v += __shfl_xor(v, 4); v += __shfl_xor(v, 8);
          if ((lane & 15) == 0) {
            int rloc = wr * 64 + mi * 16 + (lane >> 4) * 4 + reg;
            atomicAdd(&rr[ti * 128 + rloc], v * s_qs[rloc]);
          }
        }
      }
      if (!diag) {
        #pragma unroll
        for (int ni = 0; ni < 4; ++ni) {
          float s = 0.f;
          #pragma unroll
          for (int mi = 0; mi < 4; ++mi)
            #pragma unroll
            for (int reg = 0; reg < 4; ++reg) {
              int d = acc[mi][ni][reg];
              s += (d > 0 ? (float)d : 0.f) * s_qs[wr * 64 + mi * 16 + (lane >> 4) * 4 + reg];
            }
          s += __shfl_xor(s, 16); s += __shfl_xor(s, 32);
          if (lane < 16) {
            int cloc = wc * 64 + ni * 16 + lane;
            atomicAdd(&rr[tj * 128 + cloc], s * s_qs[128 + cloc]);
          }
        }
      }
      if (ti == 0 && wr == 0 && (lane >> 4) == 0) {
        float q0 = s_qs[0];
        float* scc = sc + mb * NP;
        #pragma unroll
        for (int ni = 0; ni < 4; ++ni) {
          int col = tj * 128 + wc * 64 + ni * 16 + (lane & 15);
          int d = acc[0][ni][0];                    // row 0 of G
          scc[col] = (d > 0 ? (float)d : 0.f) * q0 * qsc[ni];
        }
      }
    }
  }
  __threadfence();
  grid.sync();

  // ================= phase 2: y[mb][h] = sum_m w[m]*q[m][h] =================
  {
    float* s_w = (float*)smem;
    float (*s_part)[512] = (float(*)[512])(smem + 512);
    for (int u = blockIdx.x; u < 512; u += nb) {
      int chunk = u & 7, mb = u >> 3;
      int m0 = chunk * 128;
      const float* rr = r + mb * NP;
      if (tid < 128) {
        int m = m0 + tid;
        float wm = 0.f;
        if (m < 1001) {
          float d0 = rsqrtf(rr[0] + 1.0f);
          float dm = rsqrtf(rr[m] + 1.0f);
          wm = d0 * dm * (sc[mb * NP + m] + (m == 0 ? 1.0f : 0.0f)) * nrm[mb * NP + m] * qs[mb * NP + m];
        }
        s_w[tid] = wm;
      }
      __syncthreads();
      float a[8] = {};
      const signed char* X = xq + (size_t)mb * NP * H_ + lane * 8;
      for (int i = 0; i < 32; ++i) {
        int m = w * 32 + i;
        float wm = s_w[m];
        uint2 v = *(const uint2*)(X + (size_t)(m0 + m) * H_);
        a[0] = fmaf(wm, sc2f(v.x), a[0]);
        a[1] = fmaf(wm, sc2f(v.x >> 8), a[1]);
        a[2] = fmaf(wm, sc2f(v.x >> 16), a[2]);
        a[3] = fmaf(wm, sc2f(v.x >> 24), a[3]);
        a[4] = fmaf(wm, sc2f(v.y), a[4]);
        a[5] = fmaf(wm, sc2f(v.y >> 8), a[5]);
        a[6] = fmaf(wm, sc2f(v.y >> 16), a[6]);
        a[7] = fmaf(wm, sc2f(v.y >> 24), a[7]);
      }
      #pragma unroll
      for (int j = 0; j < 8; ++j) s_part[w][lane * 8 + j] = a[j];
      __syncthreads();
      float v0 = s_part[0][tid] + s_part[1][tid] + s_part[2][tid] + s_part[3][tid];
      float v1 = s_part[0][tid + 256] + s_part[1][tid + 256] + s_part[2][tid + 256] + s_part[3][tid + 256];
      atomicAdd(&y[mb * H_ + tid], v0);
      atomicAdd(&y[mb * H_ + tid + 256], v1);
    }
  }
  __threadfence();
  grid.sync();

  // ================= phase 3: go[b][k] += coef * tanh(y^T W + bias[0]) =================
  for (int u = blockIdx.x; u < 128; u += nb) {
    int mb = u & 63, half = u >> 6;
    int b = mb & 31, mod = mb >> 5;
    const float* W = mod ? Wit : Wtt;
    const float* bias = mod ? bit : btt;
    float coef = mod ? 0.3f : 0.7f;
    const float* yy = y + mb * H_;
    int kk = half * 256 + tid;
    float a = bias[kk];
    #pragma unroll 8
    for (int h = 0; h < H_; ++h) a = fmaf(yy[h], W[h * H_ + kk], a);
    atomicAdd(&go[b * H_ + kk], coef * tanh_fast(a));
  }
  __threadfence();
  grid.sync();

  // ================= phase 4: out = 0.5*(nrm*qs*q) + 0.5*graph_o =================
  for (int u = blockIdx.x; u < 16000; u += nb) {
    int wid = u * 4 + w;
    int mod = wid >= 32000 ? 1 : 0;
    int rrow = wid - mod * 32000;
    int b = rrow / 1000;
    int c = rrow - b * 1000;
    int mb = mod * 32 + b;
    size_t node_off = (size_t)(mb * NP + c + 1);
    float hnq = 0.5f * nrm[node_off] * qs[node_off];
    uint2 x = *(const uint2*)(xq + node_off * H_ + lane * 8);
    const float4* g4 = (const float4*)(go + b * H_ + lane * 8);
    float4 g0 = g4[0], g1 = g4[1];
    float4 o0, o1;
    o0.x = fmaf(hnq, sc2f(x.x), 0.5f * g0.x);
    o0.y = fmaf(hnq, sc2f(x.x >> 8), 0.5f * g0.y);
    o0.z = fmaf(hnq, sc2f(x.x >> 16), 0.5f * g0.z);
    o0.w = fmaf(hnq, sc2f(x.x >> 24), 0.5f * g0.w);
    o1.x = fmaf(hnq, sc2f(x.y), 0.5f * g1.x);
    o1.y = fmaf(hnq, sc2f(x.y >> 8), 0.5f * g1.y);
    o1.z = fmaf(hnq, sc2f(x.y >> 16), 0.5f * g1.z);
    o1.w = fmaf(hnq, sc2f(x.y >> 24), 0.5f * g1.w);
    float4* o4 = (float4*)(out + (size_t)wid * H_ + lane * 8);
    o4[0] = o0; o4[1] = o1;
  }
}

extern "C" void kernel_launch(void* const* d_in, const int* in_sizes, int n_in,
                              void* d_out, int out_size, void* d_ws, size_t ws_size,
                              hipStream_t stream) {
  const float* it  = (const float*)d_in[0];
  const float* ii  = (const float*)d_in[1];
  const float* bt  = (const float*)d_in[2];
  const float* bi  = (const float*)d_in[3];
  const float* Wtt = (const float*)d_in[4];
  const float* btt = (const float*)d_in[5];
  const float* Wit = (const float*)d_in[6];
  const float* bit = (const float*)d_in[7];

  char* ws = (char*)d_ws;
  signed char* xq = (signed char*)ws;                             // 33,554,432 B
  size_t off = 33554432;
  float* nrm = (float*)(ws + off); off += 262144;                 // [2][32][1024] f32
  float* qs  = (float*)(ws + off); off += 262144;
  float* sc  = (float*)(ws + off); off += 262144;
  float* r   = (float*)(ws + off); off += 262144;                 // zeroed in phase 0
  float* y   = (float*)(ws + off); off += 131072;                 // zeroed in phase 0
  float* go  = (float*)(ws + off); off += 65536;                  // zeroed in phase 0
  float* outp = (float*)d_out;

  int nbpc = 0;
  hipOccupancyMaxActiveBlocksPerMultiprocessor(&nbpc, k_mega, 256, 0);
  if (nbpc < 1) nbpc = 1;
  long long grid = (long long)nbpc * 256;   // 256 CUs on MI355X
  if (grid > 1024) grid = 1024;
  grid &= ~7LL;                             // multiple of 8: XCD pinning in gram phase
  if (grid < 8) grid = 8;

  void* args[] = {(void*)&it, (void*)&ii, (void*)&bt, (void*)&bi,
                  (void*)&Wtt, (void*)&btt, (void*)&Wit, (void*)&bit,
                  (void*)&xq, (void*)&nrm, (void*)&qs, (void*)&sc,
                  (void*)&r, (void*)&y, (void*)&go, (void*)&outp};
  hipLaunchCooperativeKernel((const void*)k_mega, dim3((unsigned)grid), dim3(256), args, 0, stream);
}

// Round 9
// 428.757 us; speedup vs baseline: 1.3441x; 1.3441x over previous
//
#include <hip/hip_runtime.h>
#include <hip/hip_bf16.h>
#include <hip/hip_cooperative_groups.h>

namespace cg = cooperative_groups;

#define B_ 32
#define C_ 1000
#define H_ 512
#define NP 1024   // padded node count (N=1001 real)

typedef __attribute__((ext_vector_type(4))) int i32x4;

// tile order per mb: 28 off-diag first, 8 diag last (last grid-stride round = diag-only, half loads)
__device__ const unsigned char TI36[36] = {0,0,0,0,0,0,0, 1,1,1,1,1,1, 2,2,2,2,2, 3,3,3,3, 4,4,4, 5,5, 6, 0,1,2,3,4,5,6,7};
__device__ const unsigned char TJ36[36] = {1,2,3,4,5,6,7, 2,3,4,5,6,7, 3,4,5,6,7, 4,5,6,7, 5,6,7, 6,7, 7, 0,1,2,3,4,5,6,7};

__device__ __forceinline__ float tanh_fast(float x) {
  float ax = fminf(fabsf(x), 15.0f);
  float e = __expf(2.0f * ax);
  float t = (e - 1.0f) / (e + 1.0f);
  return copysignf(t, x);
}
__device__ __forceinline__ float sc2f(unsigned v) {   // sext low byte -> float
  return (float)(int)(signed char)v;
}
__device__ __forceinline__ void gload16(const void* g, void* l) {
  __builtin_amdgcn_global_load_lds((const __attribute__((address_space(1))) unsigned*)g,
                                   (__attribute__((address_space(3))) unsigned*)l, 16, 0, 0);
}

// launch_bounds(256, 2): VGPR cap 256 -> gram acc[4][4]+frags (~130 live) fits with NO spill.
// (r8's (256,4) capped VGPR at 64 -> scratch-spilled accumulators -> 950us. LDS 33.8KB caps
//  occupancy at 4 blocks/CU anyway, so the looser reg bound costs nothing.)
__global__ __launch_bounds__(256, 2) void k_mega(
    const float* __restrict__ it, const float* __restrict__ ii,
    const float* __restrict__ bt, const float* __restrict__ bi,
    const float* __restrict__ Wtt, const float* __restrict__ btt,
    const float* __restrict__ Wit, const float* __restrict__ bit,
    signed char* __restrict__ xq, float* __restrict__ nrm, float* __restrict__ qs,
    float* __restrict__ sc, float* __restrict__ r, float* __restrict__ y,
    float* __restrict__ go, float* __restrict__ out) {
  cg::grid_group grid = cg::this_grid();
  __shared__ __align__(16) unsigned char smem[33792];   // gram: As 16K | Bs 16K | s_qs 1K
  const int nb = gridDim.x;
  const int tid = threadIdx.x;
  const int w = tid >> 6, lane = tid & 63;

  // ================= phase 0: normalize -> i8 quant; zero r/y/go =================
  for (int u = blockIdx.x; u < 16384; u += nb) {
    int zi = u * 256 + tid;
    if (zi < 114688) r[zi] = 0.0f;               // r,y,go contiguous

    int wid = u * 4 + w;
    int node = wid & (NP - 1);
    int mb = wid >> 10;
    int b = mb & 31, mod = mb >> 5;
    const float* src = nullptr;
    if (node == 0) src = (mod ? ii : it) + b * H_;
    else if (node <= C_) src = (mod ? bi : bt) + ((size_t)b * C_ + (node - 1)) * H_;
    float4 v0 = make_float4(0.f, 0.f, 0.f, 0.f), v1 = v0;
    if (src) {
      const float4* s4 = (const float4*)src;
      v0 = s4[lane * 2]; v1 = s4[lane * 2 + 1];
    }
    float ss = v0.x*v0.x + v0.y*v0.y + v0.z*v0.z + v0.w*v0.w
             + v1.x*v1.x + v1.y*v1.y + v1.z*v1.z + v1.w*v1.w;
    #pragma unroll
    for (int o = 32; o; o >>= 1) ss += __shfl_xor(ss, o);
    float n = sqrtf(ss);
    if (lane == 0) nrm[wid] = n;
    float inv = 1.0f / fmaxf(n, 1e-12f);
    float x[8] = {v0.x*inv, v0.y*inv, v0.z*inv, v0.w*inv, v1.x*inv, v1.y*inv, v1.z*inv, v1.w*inv};
    float m8 = 0.f;
    #pragma unroll
    for (int j = 0; j < 8; ++j) m8 = fmaxf(m8, fabsf(x[j]));
    #pragma unroll
    for (int o = 32; o; o >>= 1) m8 = fmaxf(m8, __shfl_xor(m8, o));
    if (lane == 0) qs[wid] = m8 * (1.0f / 127.0f);
    float invq = (m8 > 0.f) ? 127.0f / m8 : 0.f;
    int q[8];
    #pragma unroll
    for (int j = 0; j < 8; ++j) q[j] = __float2int_rn(x[j] * invq);
    unsigned lo = (q[0] & 255) | ((q[1] & 255) << 8) | ((q[2] & 255) << 16) | ((unsigned)(q[3] & 255) << 24);
    unsigned hi = (q[4] & 255) | ((q[5] & 255) << 8) | ((q[6] & 255) << 16) | ((unsigned)(q[7] & 255) << 24);
    *(uint2*)(xq + (size_t)wid * H_ + lane * 8) = make_uint2(lo, hi);
  }
  __threadfence();
  grid.sync();

  // ================= phase 1: i8 Gram row-sums, symmetric, dbuf + counted vmcnt =================
  {
    unsigned char* As = smem;
    unsigned char* Bs = smem + 16384;
    float* s_qs = (float*)(smem + 32768);
    const int wr = w >> 1, wc = w & 1;
    const int lrow = lane >> 2;   // row within 16-row staging chunk
    const int ps0 = lane & 3;     // physical 16B segment

    for (int u = blockIdx.x; u < 2304; u += nb) {   // u%8 == blockIdx.x%8 (nb%8==0) -> XCD-pinned
      int mb = u & 63;
      int o = u >> 6;
      int ti = TI36[o], tj = TJ36[o];
      bool diag = (ti == tj);
      const signed char* X = xq + (size_t)mb * NP * H_;

      __syncthreads();   // previous tile's epilogue reads of s_qs done
      if (tid < 128) s_qs[tid] = qs[mb * NP + ti * 128 + tid];
      else           s_qs[tid] = qs[mb * NP + tj * 128 + (tid - 128)];

      i32x4 acc[4][4] = {};
      auto stage = [&](int buf, int ks) {
        #pragma unroll
        for (int q = 0; q < 2; ++q) {
          int chunk = w * 2 + q;
          int row = chunk * 16 + lrow;
          int qq = ps0 ^ ((row >> 1) & 3);
          gload16(X + (size_t)(ti * 128 + row) * H_ + ks * 64 + qq * 16,
                  (void*)(As + buf * 8192 + chunk * 1024));
          if (!diag)
            gload16(X + (size_t)(tj * 128 + row) * H_ + ks * 64 + qq * 16,
                    (void*)(Bs + buf * 8192 + chunk * 1024));
        }
      };

      stage(0, 0);          // per-wave loads per stage: 4 (non-diag) / 2 (diag)
      stage(1, 1);
      #pragma unroll
      for (int ks = 0; ks < 8; ++ks) {
        if (ks < 7) {
          if (diag) asm volatile("s_waitcnt vmcnt(2)" ::: "memory");
          else      asm volatile("s_waitcnt vmcnt(4)" ::: "memory");
        } else {
          asm volatile("s_waitcnt vmcnt(0)" ::: "memory");
        }
        __builtin_amdgcn_s_barrier();           // buf[ks&1] fully staged
        const unsigned char* Ab = As + (ks & 1) * 8192;
        const unsigned char* Bb = (diag ? As : Bs) + (ks & 1) * 8192;
        i32x4 af[4], bf[4];
        #pragma unroll
        for (int mi = 0; mi < 4; ++mi) {
          int row = wr * 64 + mi * 16 + (lane & 15);
          int ps = (lane >> 4) ^ ((row >> 1) & 3);
          af[mi] = *(const i32x4*)(Ab + row * 64 + ps * 16);
        }
        #pragma unroll
        for (int ni = 0; ni < 4; ++ni) {
          int row = wc * 64 + ni * 16 + (lane & 15);
          int ps = (lane >> 4) ^ ((row >> 1) & 3);
          bf[ni] = *(const i32x4*)(Bb + row * 64 + ps * 16);
        }
        #pragma unroll
        for (int mi = 0; mi < 4; ++mi)
          #pragma unroll
          for (int ni = 0; ni < 4; ++ni)
            acc[mi][ni] = __builtin_amdgcn_mfma_i32_16x16x64_i8(af[mi], bf[ni], acc[mi][ni], 0, 0, 0);
        __builtin_amdgcn_s_barrier();           // all reads of buf[ks&1] retired
        if (ks < 6) stage(ks & 1, ks + 2);
      }

      __syncthreads();   // s_qs visible; LDS idle
      float* rr = r + mb * NP;
      float qsc[4];
      #pragma unroll
      for (int ni = 0; ni < 4; ++ni) qsc[ni] = s_qs[128 + wc * 64 + ni * 16 + (lane & 15)];
      #pragma unroll
      for (int mi = 0; mi < 4; ++mi) {
        #pragma unroll
        for (int reg = 0; reg < 4; ++reg) {
          float v = 0.f;
          #pragma unroll
          for (int ni = 0; ni < 4; ++ni) {
            int d = acc[mi][ni][reg];
            v += (d > 0 ? (float)d : 0.f) * qsc[ni];
          }
          v += __shfl_xor(v, 1); v += __shfl_xor(v, 2); v += __shfl_xor(v, 4); v += __shfl_xor(v, 8);
          if ((lane & 15) == 0) {
            int rloc = wr * 64 + mi * 16 + (lane >> 4) * 4 + reg;
            atomicAdd(&rr[ti * 128 + rloc], v * s_qs[rloc]);
          }
        }
      }
      if (!diag) {
        #pragma unroll
        for (int ni = 0; ni < 4; ++ni) {
          float s = 0.f;
          #pragma unroll
          for (int mi = 0; mi < 4; ++mi)
            #pragma unroll
            for (int reg = 0; reg < 4; ++reg) {
              int d = acc[mi][ni][reg];
              s += (d > 0 ? (float)d : 0.f) * s_qs[wr * 64 + mi * 16 + (lane >> 4) * 4 + reg];
            }
          s += __shfl_xor(s, 16); s += __shfl_xor(s, 32);
          if (lane < 16) {
            int cloc = wc * 64 + ni * 16 + lane;
            atomicAdd(&rr[tj * 128 + cloc], s * s_qs[128 + cloc]);
          }
        }
      }
      if (ti == 0 && wr == 0 && (lane >> 4) == 0) {
        float q0 = s_qs[0];
        float* scc = sc + mb * NP;
        #pragma unroll
        for (int ni = 0; ni < 4; ++ni) {
          int col = tj * 128 + wc * 64 + ni * 16 + (lane & 15);
          int d = acc[0][ni][0];                    // row 0 of G
          scc[col] = (d > 0 ? (float)d : 0.f) * q0 * qsc[ni];
        }
      }
    }
  }
  __threadfence();
  grid.sync();

  // ================= phase 2: y[mb][h] = sum_m w[m]*q[m][h] =================
  {
    float* s_w = (float*)smem;
    float (*s_part)[577] = (float(*)[577])(smem + 512);   // stride 577: addr=h+h/8, 32 distinct banks
    for (int u = blockIdx.x; u < 512; u += nb) {
      int chunk = u & 7, mb = u >> 3;
      int m0 = chunk * 128;
      const float* rr = r + mb * NP;
      __syncthreads();   // prior iteration's reads done before overwrite
      if (tid < 128) {
        int m = m0 + tid;
        float wm = 0.f;
        if (m < 1001) {
          float d0 = rsqrtf(rr[0] + 1.0f);
          float dm = rsqrtf(rr[m] + 1.0f);
          wm = d0 * dm * (sc[mb * NP + m] + (m == 0 ? 1.0f : 0.0f)) * nrm[mb * NP + m] * qs[mb * NP + m];
        }
        s_w[tid] = wm;
      }
      __syncthreads();
      float a[8] = {};
      const signed char* X = xq + (size_t)mb * NP * H_ + lane * 8;
      for (int i = 0; i < 32; ++i) {
        int m = w * 32 + i;
        float wm = s_w[m];
        uint2 v = *(const uint2*)(X + (size_t)(m0 + m) * H_);
        a[0] = fmaf(wm, sc2f(v.x), a[0]);
        a[1] = fmaf(wm, sc2f(v.x >> 8), a[1]);
        a[2] = fmaf(wm, sc2f(v.x >> 16), a[2]);
        a[3] = fmaf(wm, sc2f(v.x >> 24), a[3]);
        a[4] = fmaf(wm, sc2f(v.y), a[4]);
        a[5] = fmaf(wm, sc2f(v.y >> 8), a[5]);
        a[6] = fmaf(wm, sc2f(v.y >> 16), a[6]);
        a[7] = fmaf(wm, sc2f(v.y >> 24), a[7]);
      }
      #pragma unroll
      for (int j = 0; j < 8; ++j) s_part[w][lane * 9 + j] = a[j];   // h=lane*8+j at h+h/8
      __syncthreads();
      int h0 = tid, h1 = tid + 256;
      float v0 = s_part[0][h0 + (h0 >> 3)] + s_part[1][h0 + (h0 >> 3)]
               + s_part[2][h0 + (h0 >> 3)] + s_part[3][h0 + (h0 >> 3)];
      float v1 = s_part[0][h1 + (h1 >> 3)] + s_part[1][h1 + (h1 >> 3)]
               + s_part[2][h1 + (h1 >> 3)] + s_part[3][h1 + (h1 >> 3)];
      atomicAdd(&y[mb * H_ + h0], v0);
      atomicAdd(&y[mb * H_ + h1], v1);
    }
  }
  __threadfence();
  grid.sync();

  // ================= phase 3: go[b][k] += coef * tanh(y^T W + bias[0]) =================
  for (int u = blockIdx.x; u < 128; u += nb) {
    int mb = u & 63, half = u >> 6;
    int b = mb & 31, mod = mb >> 5;
    const float* W = mod ? Wit : Wtt;
    const float* bias = mod ? bit : btt;
    float coef = mod ? 0.3f : 0.7f;
    const float* yy = y + mb * H_;
    int kk = half * 256 + tid;
    float a = bias[kk];
    #pragma unroll 8
    for (int h = 0; h < H_; ++h) a = fmaf(yy[h], W[h * H_ + kk], a);
    atomicAdd(&go[b * H_ + kk], coef * tanh_fast(a));
  }
  __threadfence();
  grid.sync();

  // ================= phase 4: out = 0.5*(nrm*qs*q) + 0.5*graph_o =================
  for (int u = blockIdx.x; u < 16000; u += nb) {
    int wid = u * 4 + w;
    int mod = wid >= 32000 ? 1 : 0;
    int rrow = wid - mod * 32000;
    int b = rrow / 1000;
    int c = rrow - b * 1000;
    int mb = mod * 32 + b;
    size_t node_off = (size_t)(mb * NP + c + 1);
    float hnq = 0.5f * nrm[node_off] * qs[node_off];
    uint2 x = *(const uint2*)(xq + node_off * H_ + lane * 8);
    const float4* g4 = (const float4*)(go + b * H_ + lane * 8);
    float4 g0 = g4[0], g1 = g4[1];
    float4 o0, o1;
    o0.x = fmaf(hnq, sc2f(x.x), 0.5f * g0.x);
    o0.y = fmaf(hnq, sc2f(x.x >> 8), 0.5f * g0.y);
    o0.z = fmaf(hnq, sc2f(x.x >> 16), 0.5f * g0.z);
    o0.w = fmaf(hnq, sc2f(x.x >> 24), 0.5f * g0.w);
    o1.x = fmaf(hnq, sc2f(x.y), 0.5f * g1.x);
    o1.y = fmaf(hnq, sc2f(x.y >> 8), 0.5f * g1.y);
    o1.z = fmaf(hnq, sc2f(x.y >> 16), 0.5f * g1.z);
    o1.w = fmaf(hnq, sc2f(x.y >> 24), 0.5f * g1.w);
    float4* o4 = (float4*)(out + (size_t)wid * H_ + lane * 8);
    o4[0] = o0; o4[1] = o1;
  }
}

extern "C" void kernel_launch(void* const* d_in, const int* in_sizes, int n_in,
                              void* d_out, int out_size, void* d_ws, size_t ws_size,
                              hipStream_t stream) {
  const float* it  = (const float*)d_in[0];
  const float* ii  = (const float*)d_in[1];
  const float* bt  = (const float*)d_in[2];
  const float* bi  = (const float*)d_in[3];
  const float* Wtt = (const float*)d_in[4];
  const float* btt = (const float*)d_in[5];
  const float* Wit = (const float*)d_in[6];
  const float* bit = (const float*)d_in[7];

  char* ws = (char*)d_ws;
  signed char* xq = (signed char*)ws;                             // 33,554,432 B
  size_t off = 33554432;
  float* nrm = (float*)(ws + off); off += 262144;                 // [2][32][1024] f32
  float* qs  = (float*)(ws + off); off += 262144;
  float* sc  = (float*)(ws + off); off += 262144;
  float* r   = (float*)(ws + off); off += 262144;                 // zeroed in phase 0
  float* y   = (float*)(ws + off); off += 131072;                 // zeroed in phase 0
  float* go  = (float*)(ws + off); off += 65536;                  // zeroed in phase 0
  float* outp = (float*)d_out;

  int nbpc = 0;
  hipOccupancyMaxActiveBlocksPerMultiprocessor(&nbpc, k_mega, 256, 0);
  if (nbpc < 1) nbpc = 1;
  if (nbpc > 4) nbpc = 4;                   // LDS-capped anyway; keep co-residency safe
  long long grid = (long long)nbpc * 256;   // 256 CUs on MI355X
  grid &= ~7LL;                             // multiple of 8: XCD pinning in gram phase
  if (grid < 8) grid = 8;

  void* args[] = {(void*)&it, (void*)&ii, (void*)&bt, (void*)&bi,
                  (void*)&Wtt, (void*)&btt, (void*)&Wit, (void*)&bit,
                  (void*)&xq, (void*)&nrm, (void*)&qs, (void*)&sc,
                  (void*)&r, (void*)&y, (void*)&go, (void*)&outp};
  hipLaunchCooperativeKernel((const void*)k_mega, dim3((unsigned)grid), dim3(256), args, 0, stream);
}

// Round 10
// 132.537 us; speedup vs baseline: 4.3482x; 3.2350x over previous
//
#include <hip/hip_runtime.h>
#include <hip/hip_bf16.h>

#define B_ 32
#define C_ 1000
#define H_ 512
#define NP 1024   // padded node count (N=1001 real)

typedef __attribute__((ext_vector_type(4))) int i32x4;

__device__ __forceinline__ float tanh_fast(float x) {
  float ax = fminf(fabsf(x), 15.0f);
  float e = __expf(2.0f * ax);
  float t = (e - 1.0f) / (e + 1.0f);
  return copysignf(t, x);
}
__device__ __forceinline__ float sc2f(unsigned v) {   // sext low byte -> float
  return (float)(int)(signed char)v;
}
__device__ __forceinline__ void gload16(const void* g, void* l) {
  __builtin_amdgcn_global_load_lds((const __attribute__((address_space(1))) unsigned*)g,
                                   (__attribute__((address_space(3))) unsigned*)l, 16, 0, 0);
}

// ---------------- K1: normalize -> per-node i8 quant [2][32][1024][512]; zero r/y/go ----------------
// Block->mb mapping XCD-pinned: mb&7 == blockIdx%8, matching k_gram's consumer mapping, so
// xq writes land in the L2 slice that k_gram will read from.
__global__ __launch_bounds__(256) void k_norm(const float* __restrict__ it, const float* __restrict__ ii,
                                              const float* __restrict__ bt, const float* __restrict__ bi,
                                              signed char* __restrict__ xq, float* __restrict__ nrm,
                                              float* __restrict__ qs, float* __restrict__ zero_base) {
  int zi = blockIdx.x * 256 + threadIdx.x;
  if (zi < 114688) zero_base[zi] = 0.0f;   // r + y + go contiguous

  int u = blockIdx.x;                       // [0, 16384)
  int w = threadIdx.x >> 6, lane = threadIdx.x & 63;
  int xcd = u & 7, v = u >> 3;              // v in [0, 2048)
  int mb = (v & 7) * 8 + xcd;               // mb&7 == blockIdx%8
  int grp = v >> 3;                         // [0, 256)
  int wid = mb * NP + grp * 4 + w;
  int node = grp * 4 + w;
  int b = mb & 31, mod = mb >> 5;
  const float* src = nullptr;
  if (node == 0) src = (mod ? ii : it) + b * H_;
  else if (node <= C_) src = (mod ? bi : bt) + ((size_t)b * C_ + (node - 1)) * H_;
  float4 v0 = make_float4(0.f, 0.f, 0.f, 0.f), v1 = v0;
  if (src) {
    const float4* s4 = (const float4*)src;
    v0 = s4[lane * 2]; v1 = s4[lane * 2 + 1];
  }
  float ss = v0.x*v0.x + v0.y*v0.y + v0.z*v0.z + v0.w*v0.w
           + v1.x*v1.x + v1.y*v1.y + v1.z*v1.z + v1.w*v1.w;
  #pragma unroll
  for (int o = 32; o; o >>= 1) ss += __shfl_xor(ss, o);
  float n = sqrtf(ss);
  if (lane == 0) nrm[wid] = n;
  float inv = 1.0f / fmaxf(n, 1e-12f);
  float x[8] = {v0.x*inv, v0.y*inv, v0.z*inv, v0.w*inv, v1.x*inv, v1.y*inv, v1.z*inv, v1.w*inv};
  float m8 = 0.f;
  #pragma unroll
  for (int j = 0; j < 8; ++j) m8 = fmaxf(m8, fabsf(x[j]));
  #pragma unroll
  for (int o = 32; o; o >>= 1) m8 = fmaxf(m8, __shfl_xor(m8, o));
  if (lane == 0) qs[wid] = m8 * (1.0f / 127.0f);
  float invq = (m8 > 0.f) ? 127.0f / m8 : 0.f;
  int q[8];
  #pragma unroll
  for (int j = 0; j < 8; ++j) q[j] = __float2int_rn(x[j] * invq);
  unsigned lo = (q[0] & 255) | ((q[1] & 255) << 8) | ((q[2] & 255) << 16) | ((unsigned)(q[3] & 255) << 24);
  unsigned hi = (q[4] & 255) | ((q[5] & 255) << 8) | ((q[6] & 255) << 16) | ((unsigned)(q[7] & 255) << 24);
  *(uint2*)(xq + (size_t)wid * H_ + lane * 8) = make_uint2(lo, hi);
}

// ---------------- K2: i8 Gram row-sums (clipped), symmetric ti<=tj, dbuf LDS + COUNTED vmcnt ----------------
__global__ __launch_bounds__(256) void k_gram(const signed char* __restrict__ xq,
                                              const float* __restrict__ qs,
                                              float* __restrict__ r, float* __restrict__ sc) {
  __shared__ __align__(16) unsigned char As[2 * 128 * 64];
  __shared__ __align__(16) unsigned char Bs[2 * 128 * 64];
  __shared__ float s_qs[256];
  int orig = blockIdx.x;
  int xcd = orig & 7;                // all 36 tiles of an mb on one XCD -> slice L2-resident
  int k = orig >> 3;
  int mb = xcd + 8 * (k / 36);
  int idx = k % 36;
  int ti = 0, rem = idx;
  while (rem >= 8 - ti) { rem -= 8 - ti; ++ti; }
  int tj = ti + rem;
  bool diag = (ti == tj);
  const signed char* X = xq + (size_t)mb * NP * H_;
  int tid = threadIdx.x;
  int w = tid >> 6, lane = tid & 63;
  int wr = w >> 1, wc = w & 1;

  if (tid < 128) s_qs[tid] = qs[mb * NP + ti * 128 + tid];
  else           s_qs[tid] = qs[mb * NP + tj * 128 + (tid - 128)];

  i32x4 acc[4][4] = {};
  int lrow = lane >> 2;   // row within 16-row staging chunk
  int ps0 = lane & 3;     // physical 16B segment

  auto stage = [&](int buf, int ks) {
    #pragma unroll
    for (int q = 0; q < 2; ++q) {
      int chunk = w * 2 + q;
      int row = chunk * 16 + lrow;
      int qq = ps0 ^ ((row >> 1) & 3);  // logical k-segment at this physical slot
      gload16(X + (size_t)(ti * 128 + row) * H_ + ks * 64 + qq * 16,
              (void*)(As + buf * 8192 + chunk * 1024));
      if (!diag)
        gload16(X + (size_t)(tj * 128 + row) * H_ + ks * 64 + qq * 16,
                (void*)(Bs + buf * 8192 + chunk * 1024));
    }
  };

  stage(0, 0);          // per-wave loads per stage: 4 (non-diag) / 2 (diag)
  stage(1, 1);
  #pragma unroll
  for (int ks = 0; ks < 8; ++ks) {          // K = 8 steps x 64
    // wait only for buf[ks&1]'s loads; leave the next stage's loads in flight (T4)
    if (ks < 7) {
      if (diag) asm volatile("s_waitcnt vmcnt(2)" ::: "memory");
      else      asm volatile("s_waitcnt vmcnt(4)" ::: "memory");
    } else {
      asm volatile("s_waitcnt vmcnt(0)" ::: "memory");
    }
    __builtin_amdgcn_s_barrier();           // buf[ks&1] fully staged by all waves
    const unsigned char* Ab = As + (ks & 1) * 8192;
    const unsigned char* Bb = (diag ? As : Bs) + (ks & 1) * 8192;
    i32x4 af[4], bf[4];
    #pragma unroll
    for (int mi = 0; mi < 4; ++mi) {
      int row = wr * 64 + mi * 16 + (lane & 15);
      int ps = (lane >> 4) ^ ((row >> 1) & 3);
      af[mi] = *(const i32x4*)(Ab + row * 64 + ps * 16);
    }
    #pragma unroll
    for (int ni = 0; ni < 4; ++ni) {
      int row = wc * 64 + ni * 16 + (lane & 15);
      int ps = (lane >> 4) ^ ((row >> 1) & 3);
      bf[ni] = *(const i32x4*)(Bb + row * 64 + ps * 16);
    }
    #pragma unroll
    for (int mi = 0; mi < 4; ++mi)
      #pragma unroll
      for (int ni = 0; ni < 4; ++ni)
        acc[mi][ni] = __builtin_amdgcn_mfma_i32_16x16x64_i8(af[mi], bf[ni], acc[mi][ni], 0, 0, 0);
    __builtin_amdgcn_s_barrier();           // all waves' ds_reads of buf[ks&1] retired
    if (ks < 6) stage(ks & 1, ks + 2);      // safe to overwrite now
  }

  __syncthreads();   // s_qs visible (and final drain)
  // epilogue: clip (int), dequant via qs, row/col sums. C/D: col=lane&15, row=(lane>>4)*4+reg
  float* rr = r + mb * NP;
  float qsc[4];
  #pragma unroll
  for (int ni = 0; ni < 4; ++ni) qsc[ni] = s_qs[128 + wc * 64 + ni * 16 + (lane & 15)];
  #pragma unroll
  for (int mi = 0; mi < 4; ++mi) {
    #pragma unroll
    for (int reg = 0; reg < 4; ++reg) {
      float v = 0.f;
      #pragma unroll
      for (int ni = 0; ni < 4; ++ni) {
        int d = acc[mi][ni][reg];
        v += (d > 0 ? (float)d : 0.f) * qsc[ni];
      }
      v += __shfl_xor(v, 1); v += __shfl_xor(v, 2); v += __shfl_xor(v, 4); v += __shfl_xor(v, 8);
      if ((lane & 15) == 0) {
        int rloc = wr * 64 + mi * 16 + (lane >> 4) * 4 + reg;
        atomicAdd(&rr[ti * 128 + rloc], v * s_qs[rloc]);
      }
    }
  }
  if (!diag) {
    #pragma unroll
    for (int ni = 0; ni < 4; ++ni) {
      float s = 0.f;
      #pragma unroll
      for (int mi = 0; mi < 4; ++mi)
        #pragma unroll
        for (int reg = 0; reg < 4; ++reg) {
          int d = acc[mi][ni][reg];
          s += (d > 0 ? (float)d : 0.f) * s_qs[wr * 64 + mi * 16 + (lane >> 4) * 4 + reg];
        }
      s += __shfl_xor(s, 16); s += __shfl_xor(s, 32);
      if (lane < 16) {
        int cloc = wc * 64 + ni * 16 + lane;
        atomicAdd(&rr[tj * 128 + cloc], s * s_qs[128 + cloc]);
      }
    }
  }
  if (ti == 0 && wr == 0 && (lane >> 4) == 0) {
    float q0 = s_qs[0];
    float* scc = sc + mb * NP;
    #pragma unroll
    for (int ni = 0; ni < 4; ++ni) {
      int col = tj * 128 + wc * 64 + ni * 16 + (lane & 15);
      int d = acc[0][ni][0];                    // row 0 of G
      scc[col] = (d > 0 ? (float)d : 0.f) * q0 * qsc[ni];
    }
  }
}

// ---------------- K3: y[mb][h] = sum_m w[m] * q[mb][m][h]; XCD-pinned mb mapping ----------------
__global__ __launch_bounds__(256) void k_y(const signed char* __restrict__ xq,
                                           const float* __restrict__ r, const float* __restrict__ sc,
                                           const float* __restrict__ nrm, const float* __restrict__ qs,
                                           float* __restrict__ y) {
  __shared__ float s_w[128];
  __shared__ __align__(16) float s_part[4][512];
  int bid = blockIdx.x;                     // [0,512)
  int xcd = bid & 7, v = bid >> 3;          // v in [0,64)
  int mb = (v & 7) * 8 + xcd;               // mb&7 == blockIdx%8 (matches producer)
  int chunk = v >> 3;                       // [0,8)
  int m0 = chunk * 128;
  int t = threadIdx.x;
  const float* rr = r + mb * NP;
  if (t < 128) {
    int m = m0 + t;
    float wm = 0.f;
    if (m < 1001) {
      float d0 = rsqrtf(rr[0] + 1.0f);
      float dm = rsqrtf(rr[m] + 1.0f);
      wm = d0 * dm * (sc[mb * NP + m] + (m == 0 ? 1.0f : 0.0f)) * nrm[mb * NP + m] * qs[mb * NP + m];
    }
    s_w[t] = wm;
  }
  __syncthreads();
  int w = t >> 6, lane = t & 63;
  float a[8] = {};
  const signed char* X = xq + (size_t)mb * NP * H_ + lane * 8;
  for (int i = 0; i < 32; ++i) {
    int m = w * 32 + i;
    float wm = s_w[m];
    uint2 vv = *(const uint2*)(X + (size_t)(m0 + m) * H_);
    a[0] = fmaf(wm, sc2f(vv.x), a[0]);
    a[1] = fmaf(wm, sc2f(vv.x >> 8), a[1]);
    a[2] = fmaf(wm, sc2f(vv.x >> 16), a[2]);
    a[3] = fmaf(wm, sc2f(vv.x >> 24), a[3]);
    a[4] = fmaf(wm, sc2f(vv.y), a[4]);
    a[5] = fmaf(wm, sc2f(vv.y >> 8), a[5]);
    a[6] = fmaf(wm, sc2f(vv.y >> 16), a[6]);
    a[7] = fmaf(wm, sc2f(vv.y >> 24), a[7]);
  }
  #pragma unroll
  for (int j = 0; j < 8; ++j) s_part[w][lane * 8 + j] = a[j];
  __syncthreads();
  float v0 = s_part[0][t] + s_part[1][t] + s_part[2][t] + s_part[3][t];
  float v1 = s_part[0][t + 256] + s_part[1][t + 256] + s_part[2][t + 256] + s_part[3][t + 256];
  atomicAdd(&y[mb * H_ + t], v0);
  atomicAdd(&y[mb * H_ + t + 256], v1);
}

// ---------------- K4: go[b][k] += coef_mod * tanh(y[mb]^T W_mod + b_mod[0]) ----------------
__global__ __launch_bounds__(256) void k_go(const float* __restrict__ y,
                                            const float* __restrict__ Wtt, const float* __restrict__ btt,
                                            const float* __restrict__ Wit, const float* __restrict__ bit,
                                            float* __restrict__ go) {
  int bid = blockIdx.x;          // 0..127: (half, mb)
  int mb = bid & 63, half = bid >> 6;
  int b = mb & 31, mod = mb >> 5;
  const float* W = mod ? Wit : Wtt;
  const float* bias = mod ? bit : btt;
  float coef = mod ? 0.3f : 0.7f;
  const float* yy = y + mb * H_;
  int k = half * 256 + threadIdx.x;
  float a = bias[k];
  #pragma unroll 8
  for (int h = 0; h < H_; ++h) a = fmaf(yy[h], W[h * H_ + k], a);
  atomicAdd(&go[b * H_ + k], coef * tanh_fast(a));
}

// ---------------- K5: out = 0.5*(nrm*qs*q) + 0.5*graph_o; XCD-pinned mb mapping ----------------
__global__ __launch_bounds__(256) void k_out(const signed char* __restrict__ xq,
                                             const float* __restrict__ nrm, const float* __restrict__ qs,
                                             const float* __restrict__ go, float* __restrict__ out) {
  int u = blockIdx.x;                       // [0,16000)
  int w = threadIdx.x >> 6, lane = threadIdx.x & 63;
  int xcd = u & 7, v = u >> 3;              // v in [0,2000)
  int mbix = v / 250;                       // [0,8)
  int rowgrp = v - mbix * 250;              // [0,250)
  int mb = mbix * 8 + xcd;                  // mb&7 == blockIdx%8
  int mod = mb >> 5, b = mb & 31;
  int c = rowgrp * 4 + w;                   // [0,1000)
  size_t node_off = (size_t)(mb * NP + c + 1);
  float hnq = 0.5f * nrm[node_off] * qs[node_off];
  uint2 x = *(const uint2*)(xq + node_off * H_ + lane * 8);
  const float4* g4 = (const float4*)(go + b * H_ + lane * 8);
  float4 g0 = g4[0], g1 = g4[1];
  float4 o0, o1;
  o0.x = fmaf(hnq, sc2f(x.x), 0.5f * g0.x);
  o0.y = fmaf(hnq, sc2f(x.x >> 8), 0.5f * g0.y);
  o0.z = fmaf(hnq, sc2f(x.x >> 16), 0.5f * g0.z);
  o0.w = fmaf(hnq, sc2f(x.x >> 24), 0.5f * g0.w);
  o1.x = fmaf(hnq, sc2f(x.y), 0.5f * g1.x);
  o1.y = fmaf(hnq, sc2f(x.y >> 8), 0.5f * g1.y);
  o1.z = fmaf(hnq, sc2f(x.y >> 16), 0.5f * g1.z);
  o1.w = fmaf(hnq, sc2f(x.y >> 24), 0.5f * g1.w);
  size_t orow = (size_t)(mod * 32000 + b * 1000 + c);
  float4* o4 = (float4*)(out + orow * H_ + lane * 8);
  o4[0] = o0; o4[1] = o1;
}

extern "C" void kernel_launch(void* const* d_in, const int* in_sizes, int n_in,
                              void* d_out, int out_size, void* d_ws, size_t ws_size,
                              hipStream_t stream) {
  const float* it  = (const float*)d_in[0];
  const float* ii  = (const float*)d_in[1];
  const float* bt  = (const float*)d_in[2];
  const float* bi  = (const float*)d_in[3];
  const float* Wtt = (const float*)d_in[4];
  const float* btt = (const float*)d_in[5];
  const float* Wit = (const float*)d_in[6];
  const float* bit = (const float*)d_in[7];

  char* ws = (char*)d_ws;
  signed char* xq = (signed char*)ws;                             // 2*32*1024*512 i8 = 33,554,432 B
  size_t off = 33554432;
  float* nrm = (float*)(ws + off); off += 262144;                 // [2][32][1024] f32
  float* qs  = (float*)(ws + off); off += 262144;
  float* sc  = (float*)(ws + off); off += 262144;
  float* r   = (float*)(ws + off); off += 262144;                 // zeroed in k_norm
  float* y   = (float*)(ws + off); off += 131072;                 // zeroed in k_norm
  float* go  = (float*)(ws + off); off += 65536;                  // zeroed in k_norm

  k_norm<<<16384, 256, 0, stream>>>(it, ii, bt, bi, xq, nrm, qs, r /* r,y,go contiguous */);
  k_gram<<<64 * 36, 256, 0, stream>>>(xq, qs, r, sc);
  k_y<<<512, 256, 0, stream>>>(xq, r, sc, nrm, qs, y);
  k_go<<<128, 256, 0, stream>>>(y, Wtt, btt, Wit, bit, go);
  k_out<<<16000, 256, 0, stream>>>(xq, nrm, qs, go, (float*)d_out);
}

// Round 11
// 127.895 us; speedup vs baseline: 4.5061x; 1.0363x over previous
//
#include <hip/hip_runtime.h>
#include <hip/hip_bf16.h>

#define B_ 32
#define C_ 1000
#define H_ 512
#define NP 1024   // padded node count (N=1001 real)

typedef __attribute__((ext_vector_type(4))) int i32x4;

__device__ __forceinline__ float tanh_fast(float x) {
  float ax = fminf(fabsf(x), 15.0f);
  float e = __expf(2.0f * ax);
  float t = (e - 1.0f) / (e + 1.0f);
  return copysignf(t, x);
}
__device__ __forceinline__ float sc2f(unsigned v) {   // sext low byte -> float
  return (float)(int)(signed char)v;
}
__device__ __forceinline__ void gload16(const void* g, void* l) {
  __builtin_amdgcn_global_load_lds((const __attribute__((address_space(1))) unsigned*)g,
                                   (__attribute__((address_space(3))) unsigned*)l, 16, 0, 0);
}

// ---------------- K1: normalize -> per-node i8 quant [2][32][1024][512]; zero r/y/go ----------------
// Block->mb mapping XCD-pinned: mb&7 == blockIdx%8, matching k_gram's consumer mapping.
__global__ __launch_bounds__(256) void k_norm(const float* __restrict__ it, const float* __restrict__ ii,
                                              const float* __restrict__ bt, const float* __restrict__ bi,
                                              signed char* __restrict__ xq, float* __restrict__ nrm,
                                              float* __restrict__ qs, float* __restrict__ zero_base) {
  int zi = blockIdx.x * 256 + threadIdx.x;
  if (zi < 114688) zero_base[zi] = 0.0f;   // r + y + go contiguous

  int u = blockIdx.x;                       // [0, 16384)
  int w = threadIdx.x >> 6, lane = threadIdx.x & 63;
  int xcd = u & 7, v = u >> 3;              // v in [0, 2048)
  int mb = (v & 7) * 8 + xcd;               // mb&7 == blockIdx%8
  int grp = v >> 3;                         // [0, 256)
  int wid = mb * NP + grp * 4 + w;
  int node = grp * 4 + w;
  int b = mb & 31, mod = mb >> 5;
  const float* src = nullptr;
  if (node == 0) src = (mod ? ii : it) + b * H_;
  else if (node <= C_) src = (mod ? bi : bt) + ((size_t)b * C_ + (node - 1)) * H_;
  float4 v0 = make_float4(0.f, 0.f, 0.f, 0.f), v1 = v0;
  if (src) {
    const float4* s4 = (const float4*)src;
    v0 = s4[lane * 2]; v1 = s4[lane * 2 + 1];
  }
  float ss = v0.x*v0.x + v0.y*v0.y + v0.z*v0.z + v0.w*v0.w
           + v1.x*v1.x + v1.y*v1.y + v1.z*v1.z + v1.w*v1.w;
  #pragma unroll
  for (int o = 32; o; o >>= 1) ss += __shfl_xor(ss, o);
  float n = sqrtf(ss);
  if (lane == 0) nrm[wid] = n;
  float inv = 1.0f / fmaxf(n, 1e-12f);
  float x[8] = {v0.x*inv, v0.y*inv, v0.z*inv, v0.w*inv, v1.x*inv, v1.y*inv, v1.z*inv, v1.w*inv};
  float m8 = 0.f;
  #pragma unroll
  for (int j = 0; j < 8; ++j) m8 = fmaxf(m8, fabsf(x[j]));
  #pragma unroll
  for (int o = 32; o; o >>= 1) m8 = fmaxf(m8, __shfl_xor(m8, o));
  if (lane == 0) qs[wid] = m8 * (1.0f / 127.0f);
  float invq = (m8 > 0.f) ? 127.0f / m8 : 0.f;
  int q[8];
  #pragma unroll
  for (int j = 0; j < 8; ++j) q[j] = __float2int_rn(x[j] * invq);
  unsigned lo = (q[0] & 255) | ((q[1] & 255) << 8) | ((q[2] & 255) << 16) | ((unsigned)(q[3] & 255) << 24);
  unsigned hi = (q[4] & 255) | ((q[5] & 255) << 8) | ((q[6] & 255) << 16) | ((unsigned)(q[7] & 255) << 24);
  *(uint2*)(xq + (size_t)wid * H_ + lane * 8) = make_uint2(lo, hi);
}

// ---------------- K2: i8 Gram row-sums, symmetric ti<=tj. 3-buffer LDS, ONE barrier/K-step ----------------
// Safety argument for single barrier: a wave's ds_reads of step s-1 must retire before its MFMAs
// issue (register dependency), and MFMAs precede its barrier arrival. So after the rendezvous at
// step s, ALL waves' step s-1 reads are retired -> staging buf (s+2)%3 (last read at step s-1) is safe.
__global__ __launch_bounds__(256) void k_gram(const signed char* __restrict__ xq,
                                              const float* __restrict__ qs,
                                              float* __restrict__ r, float* __restrict__ sc) {
  __shared__ __align__(16) unsigned char As[3 * 8192];
  __shared__ __align__(16) unsigned char Bs[3 * 8192];
  __shared__ float s_qs[256];
  int orig = blockIdx.x;
  int xcd = orig & 7;                // all 36 tiles of an mb on one XCD -> slice L2-resident
  int k = orig >> 3;
  int mb = xcd + 8 * (k / 36);
  int idx = k % 36;
  int ti = 0, rem = idx;
  while (rem >= 8 - ti) { rem -= 8 - ti; ++ti; }
  int tj = ti + rem;
  bool diag = (ti == tj);
  const signed char* X = xq + (size_t)mb * NP * H_;
  int tid = threadIdx.x;
  int w = tid >> 6, lane = tid & 63;
  int wr = w >> 1, wc = w & 1;

  if (tid < 128) s_qs[tid] = qs[mb * NP + ti * 128 + tid];
  else           s_qs[tid] = qs[mb * NP + tj * 128 + (tid - 128)];

  i32x4 acc[4][4] = {};
  int lrow = lane >> 2;   // row within 16-row staging chunk
  int ps0 = lane & 3;     // physical 16B segment

  auto stage = [&](int buf, int ks) {
    #pragma unroll
    for (int q = 0; q < 2; ++q) {
      int chunk = w * 2 + q;
      int row = chunk * 16 + lrow;
      int qq = ps0 ^ ((row >> 1) & 3);  // logical k-segment at this physical slot
      gload16(X + (size_t)(ti * 128 + row) * H_ + ks * 64 + qq * 16,
              (void*)(As + buf * 8192 + chunk * 1024));
      if (!diag)
        gload16(X + (size_t)(tj * 128 + row) * H_ + ks * 64 + qq * 16,
                (void*)(Bs + buf * 8192 + chunk * 1024));
    }
  };

  auto do_step = [&](const unsigned char* Ab, const unsigned char* Bb) {
    i32x4 af[4], bf[4];
    #pragma unroll
    for (int mi = 0; mi < 4; ++mi) {
      int row = wr * 64 + mi * 16 + (lane & 15);
      int ps = (lane >> 4) ^ ((row >> 1) & 3);
      af[mi] = *(const i32x4*)(Ab + row * 64 + ps * 16);
    }
    #pragma unroll
    for (int ni = 0; ni < 4; ++ni) {
      int row = wc * 64 + ni * 16 + (lane & 15);
      int ps = (lane >> 4) ^ ((row >> 1) & 3);
      bf[ni] = *(const i32x4*)(Bb + row * 64 + ps * 16);
    }
    #pragma unroll
    for (int mi = 0; mi < 4; ++mi)
      #pragma unroll
      for (int ni = 0; ni < 4; ++ni)
        acc[mi][ni] = __builtin_amdgcn_mfma_i32_16x16x64_i8(af[mi], bf[ni], acc[mi][ni], 0, 0, 0);
  };

  stage(0, 0); stage(1, 1); stage(2, 2);   // 3 stages in flight
  if (!diag) {                              // 4 loads per stage
    #pragma unroll
    for (int ks = 0; ks < 8; ++ks) {
      if (ks == 0)      asm volatile("s_waitcnt vmcnt(8)" ::: "memory");   // drain stage 0, keep 1,2
      else if (ks < 7)  asm volatile("s_waitcnt vmcnt(4)" ::: "memory");   // drain stage ks, keep ks+1
      else              asm volatile("s_waitcnt vmcnt(0)" ::: "memory");
      __builtin_amdgcn_s_barrier();          // buf ks%3 staged everywhere; step ks-1 reads all retired
      if (ks >= 1 && ks <= 5) stage((ks + 2) % 3, ks + 2);
      do_step(As + (ks % 3) * 8192, Bs + (ks % 3) * 8192);
    }
  } else {                                   // 2 loads per stage
    #pragma unroll
    for (int ks = 0; ks < 8; ++ks) {
      if (ks == 0)      asm volatile("s_waitcnt vmcnt(4)" ::: "memory");
      else if (ks < 7)  asm volatile("s_waitcnt vmcnt(2)" ::: "memory");
      else              asm volatile("s_waitcnt vmcnt(0)" ::: "memory");
      __builtin_amdgcn_s_barrier();
      if (ks >= 1 && ks <= 5) stage((ks + 2) % 3, ks + 2);
      do_step(As + (ks % 3) * 8192, As + (ks % 3) * 8192);
    }
  }

  __syncthreads();   // s_qs visible (and final drain)
  // epilogue: clip (int), dequant via qs, row/col sums. C/D: col=lane&15, row=(lane>>4)*4+reg
  float* rr = r + mb * NP;
  float qsc[4];
  #pragma unroll
  for (int ni = 0; ni < 4; ++ni) qsc[ni] = s_qs[128 + wc * 64 + ni * 16 + (lane & 15)];
  #pragma unroll
  for (int mi = 0; mi < 4; ++mi) {
    #pragma unroll
    for (int reg = 0; reg < 4; ++reg) {
      float v = 0.f;
      #pragma unroll
      for (int ni = 0; ni < 4; ++ni) {
        int d = acc[mi][ni][reg];
        v += (d > 0 ? (float)d : 0.f) * qsc[ni];
      }
      v += __shfl_xor(v, 1); v += __shfl_xor(v, 2); v += __shfl_xor(v, 4); v += __shfl_xor(v, 8);
      if ((lane & 15) == 0) {
        int rloc = wr * 64 + mi * 16 + (lane >> 4) * 4 + reg;
        atomicAdd(&rr[ti * 128 + rloc], v * s_qs[rloc]);
      }
    }
  }
  if (!diag) {
    #pragma unroll
    for (int ni = 0; ni < 4; ++ni) {
      float s = 0.f;
      #pragma unroll
      for (int mi = 0; mi < 4; ++mi)
        #pragma unroll
        for (int reg = 0; reg < 4; ++reg) {
          int d = acc[mi][ni][reg];
          s += (d > 0 ? (float)d : 0.f) * s_qs[wr * 64 + mi * 16 + (lane >> 4) * 4 + reg];
        }
      s += __shfl_xor(s, 16); s += __shfl_xor(s, 32);
      if (lane < 16) {
        int cloc = wc * 64 + ni * 16 + lane;
        atomicAdd(&rr[tj * 128 + cloc], s * s_qs[128 + cloc]);
      }
    }
  }
  if (ti == 0 && wr == 0 && (lane >> 4) == 0) {
    float q0 = s_qs[0];
    float* scc = sc + mb * NP;
    #pragma unroll
    for (int ni = 0; ni < 4; ++ni) {
      int col = tj * 128 + wc * 64 + ni * 16 + (lane & 15);
      int d = acc[0][ni][0];                    // row 0 of G
      scc[col] = (d > 0 ? (float)d : 0.f) * q0 * qsc[ni];
    }
  }
}

// ---------------- K3: y[mb][h] = sum_m w[m] * q[mb][m][h]; XCD-pinned mb mapping ----------------
__global__ __launch_bounds__(256) void k_y(const signed char* __restrict__ xq,
                                           const float* __restrict__ r, const float* __restrict__ sc,
                                           const float* __restrict__ nrm, const float* __restrict__ qs,
                                           float* __restrict__ y) {
  __shared__ float s_w[128];
  __shared__ __align__(16) float s_part[4][512];
  int bid = blockIdx.x;                     // [0,512)
  int xcd = bid & 7, v = bid >> 3;          // v in [0,64)
  int mb = (v & 7) * 8 + xcd;               // mb&7 == blockIdx%8 (matches producer)
  int chunk = v >> 3;                       // [0,8)
  int m0 = chunk * 128;
  int t = threadIdx.x;
  const float* rr = r + mb * NP;
  if (t < 128) {
    int m = m0 + t;
    float wm = 0.f;
    if (m < 1001) {
      float d0 = rsqrtf(rr[0] + 1.0f);
      float dm = rsqrtf(rr[m] + 1.0f);
      wm = d0 * dm * (sc[mb * NP + m] + (m == 0 ? 1.0f : 0.0f)) * nrm[mb * NP + m] * qs[mb * NP + m];
    }
    s_w[t] = wm;
  }
  __syncthreads();
  int w = t >> 6, lane = t & 63;
  float a[8] = {};
  const signed char* X = xq + (size_t)mb * NP * H_ + lane * 8;
  for (int i = 0; i < 32; ++i) {
    int m = w * 32 + i;
    float wm = s_w[m];
    uint2 vv = *(const uint2*)(X + (size_t)(m0 + m) * H_);
    a[0] = fmaf(wm, sc2f(vv.x), a[0]);
    a[1] = fmaf(wm, sc2f(vv.x >> 8), a[1]);
    a[2] = fmaf(wm, sc2f(vv.x >> 16), a[2]);
    a[3] = fmaf(wm, sc2f(vv.x >> 24), a[3]);
    a[4] = fmaf(wm, sc2f(vv.y), a[4]);
    a[5] = fmaf(wm, sc2f(vv.y >> 8), a[5]);
    a[6] = fmaf(wm, sc2f(vv.y >> 16), a[6]);
    a[7] = fmaf(wm, sc2f(vv.y >> 24), a[7]);
  }
  #pragma unroll
  for (int j = 0; j < 8; ++j) s_part[w][lane * 8 + j] = a[j];
  __syncthreads();
  float v0 = s_part[0][t] + s_part[1][t] + s_part[2][t] + s_part[3][t];
  float v1 = s_part[0][t + 256] + s_part[1][t + 256] + s_part[2][t + 256] + s_part[3][t + 256];
  atomicAdd(&y[mb * H_ + t], v0);
  atomicAdd(&y[mb * H_ + t + 256], v1);
}

// ---------------- K4: go[b][k] += coef_mod * tanh(y[mb]^T W_mod + b_mod[0]) ----------------
__global__ __launch_bounds__(256) void k_go(const float* __restrict__ y,
                                            const float* __restrict__ Wtt, const float* __restrict__ btt,
                                            const float* __restrict__ Wit, const float* __restrict__ bit,
                                            float* __restrict__ go) {
  int bid = blockIdx.x;          // 0..127: (half, mb)
  int mb = bid & 63, half = bid >> 6;
  int b = mb & 31, mod = mb >> 5;
  const float* W = mod ? Wit : Wtt;
  const float* bias = mod ? bit : btt;
  float coef = mod ? 0.3f : 0.7f;
  const float* yy = y + mb * H_;
  int k = half * 256 + threadIdx.x;
  float a = bias[k];
  #pragma unroll 8
  for (int h = 0; h < H_; ++h) a = fmaf(yy[h], W[h * H_ + k], a);
  atomicAdd(&go[b * H_ + k], coef * tanh_fast(a));
}

// ---------------- K5: out = 0.5*(nrm*qs*q) + 0.5*graph_o; XCD-pinned mb mapping ----------------
__global__ __launch_bounds__(256) void k_out(const signed char* __restrict__ xq,
                                             const float* __restrict__ nrm, const float* __restrict__ qs,
                                             const float* __restrict__ go, float* __restrict__ out) {
  int u = blockIdx.x;                       // [0,16000)
  int w = threadIdx.x >> 6, lane = threadIdx.x & 63;
  int xcd = u & 7, v = u >> 3;              // v in [0,2000)
  int mbix = v / 250;                       // [0,8)
  int rowgrp = v - mbix * 250;              // [0,250)
  int mb = mbix * 8 + xcd;                  // mb&7 == blockIdx%8
  int mod = mb >> 5, b = mb & 31;
  int c = rowgrp * 4 + w;                   // [0,1000)
  size_t node_off = (size_t)(mb * NP + c + 1);
  float hnq = 0.5f * nrm[node_off] * qs[node_off];
  uint2 x = *(const uint2*)(xq + node_off * H_ + lane * 8);
  const float4* g4 = (const float4*)(go + b * H_ + lane * 8);
  float4 g0 = g4[0], g1 = g4[1];
  float4 o0, o1;
  o0.x = fmaf(hnq, sc2f(x.x), 0.5f * g0.x);
  o0.y = fmaf(hnq, sc2f(x.x >> 8), 0.5f * g0.y);
  o0.z = fmaf(hnq, sc2f(x.x >> 16), 0.5f * g0.z);
  o0.w = fmaf(hnq, sc2f(x.x >> 24), 0.5f * g0.w);
  o1.x = fmaf(hnq, sc2f(x.y), 0.5f * g1.x);
  o1.y = fmaf(hnq, sc2f(x.y >> 8), 0.5f * g1.y);
  o1.z = fmaf(hnq, sc2f(x.y >> 16), 0.5f * g1.z);
  o1.w = fmaf(hnq, sc2f(x.y >> 24), 0.5f * g1.w);
  size_t orow = (size_t)(mod * 32000 + b * 1000 + c);
  float4* o4 = (float4*)(out + orow * H_ + lane * 8);
  o4[0] = o0; o4[1] = o1;
}

extern "C" void kernel_launch(void* const* d_in, const int* in_sizes, int n_in,
                              void* d_out, int out_size, void* d_ws, size_t ws_size,
                              hipStream_t stream) {
  const float* it  = (const float*)d_in[0];
  const float* ii  = (const float*)d_in[1];
  const float* bt  = (const float*)d_in[2];
  const float* bi  = (const float*)d_in[3];
  const float* Wtt = (const float*)d_in[4];
  const float* btt = (const float*)d_in[5];
  const float* Wit = (const float*)d_in[6];
  const float* bit = (const float*)d_in[7];

  char* ws = (char*)d_ws;
  signed char* xq = (signed char*)ws;                             // 2*32*1024*512 i8 = 33,554,432 B
  size_t off = 33554432;
  float* nrm = (float*)(ws + off); off += 262144;                 // [2][32][1024] f32
  float* qs  = (float*)(ws + off); off += 262144;
  float* sc  = (float*)(ws + off); off += 262144;
  float* r   = (float*)(ws + off); off += 262144;                 // zeroed in k_norm
  float* y   = (float*)(ws + off); off += 131072;                 // zeroed in k_norm
  float* go  = (float*)(ws + off); off += 65536;                  // zeroed in k_norm

  k_norm<<<16384, 256, 0, stream>>>(it, ii, bt, bi, xq, nrm, qs, r /* r,y,go contiguous */);
  k_gram<<<64 * 36, 256, 0, stream>>>(xq, qs, r, sc);
  k_y<<<512, 256, 0, stream>>>(xq, r, sc, nrm, qs, y);
  k_go<<<128, 256, 0, stream>>>(y, Wtt, btt, Wit, bit, go);
  k_out<<<16000, 256, 0, stream>>>(xq, nrm, qs, go, (float*)d_out);
}